// Round 2
// baseline (255.930 us; speedup 1.0000x reference)
//
#include <hip/hip_runtime.h>
#include <math.h>

// Problem constants (from reference setup_inputs).
constexpr int B_ = 2048;
constexpr int C_ = 9605;
constexpr int L_ = 8;
constexpr int TOPK_ = 16;
constexpr int CAP_ = 1024;      // LDS candidate capacity (expected ~219 per row)
constexpr float T0_ = 2.0f;     // candidate prefilter threshold (16th largest ~2.95)

__device__ __forceinline__ float sigm(float v) { return 1.0f / (1.0f + expf(-v)); }

// our_rank_loss: d = x2 - x1 + margin; s = sigmoid(5d); 2s when violated (d>0)
__device__ __forceinline__ float rank_loss(float x1, float x2) {
  float d = x2 - x1 + 0.05f;
  float s = 1.0f / (1.0f + expf(-5.0f * d));
  return (d > 0.0f) ? 2.0f * s : s;
}

// Order-preserving float->uint key (ascending) and inverse.
__device__ __forceinline__ unsigned int fkey(float v) {
  unsigned int u = __float_as_uint(v);
  return u ^ ((u & 0x80000000u) ? 0xFFFFFFFFu : 0x80000000u);
}
__device__ __forceinline__ float fkeyinv(unsigned int k) {
  unsigned int u = (k & 0x80000000u) ? (k ^ 0x80000000u) : ~k;
  return __uint_as_float(u);
}

// Kernel 0: compact group_mask [L, C] (int32 0/1 — bools are promoted to int by
// the harness) -> per-class group code byte (group id, or 0xFF if none).
__global__ void build_code_kernel(const int* __restrict__ mask,
                                  unsigned char* __restrict__ code) {
  int c = blockIdx.x * 256 + threadIdx.x;
  if (c >= C_) return;
  unsigned char cd = 0xFF;
#pragma unroll
  for (int l = L_ - 1; l >= 0; --l)
    if (mask[l * C_ + c] != 0) cd = (unsigned char)l;
  code[c] = cd;
}

// Kernel 1: one block per row. Fused pass over x/y/y_neg computing group maxima,
// gt bits, top-16-candidate set; then exact 16th-largest + loss epilogue.
__global__ void __launch_bounds__(256) row_loss_kernel(
    const float* __restrict__ x, const float* __restrict__ y,
    const float* __restrict__ yn, const unsigned char* __restrict__ code,
    float* __restrict__ loss) {
  __shared__ float slot[L_ * 256];   // per-thread running max of x per group; [l][256] -> conflict-free
  __shared__ float cand[CAP_];
  __shared__ int cand_cnt;
  __shared__ unsigned int gt_bits, gtn_bits;
  __shared__ float s_x16;
  __shared__ int s_red;

  const int t = threadIdx.x;
  const int b = blockIdx.x;
  const float* xr = x + (size_t)b * C_;
  const float* yr = y + (size_t)b * C_;
  const float* ynr = yn + (size_t)b * C_;

#pragma unroll
  for (int l = 0; l < L_; ++l) slot[(l << 8) + t] = -INFINITY;
  if (t == 0) { cand_cnt = 0; gt_bits = 0u; gtn_bits = 0u; }
  __syncthreads();

  auto elem = [&](int /*c*/, unsigned char cd, float xv, float yv, float ynv) {
    if (cd < L_) {
      int a = ((int)cd << 8) + t;          // private per-thread slot, bank = t%32
      if (xv > slot[a]) slot[a] = xv;
      if (yv > 0.0f) atomicOr(&gt_bits, 1u << cd);
      if (ynv > 0.0f) atomicOr(&gtn_bits, 1u << cd);
    }
    if (xv > T0_) {
      int p = atomicAdd(&cand_cnt, 1);
      if (p < CAP_) cand[p] = xv;
    }
  };

  // Row base is misaligned by (b*C)%4 elements (C % 4 == 1): scalar head/tail,
  // aligned float4 body (coalesced 16B/lane).
  const int lead = (4 - ((b * C_) & 3)) & 3;
  const int n4 = (C_ - lead) >> 2;
  for (int j = t; j < n4; j += 256) {
    int c0 = lead + (j << 2);
    float4 xv = *reinterpret_cast<const float4*>(xr + c0);
    float4 yv = *reinterpret_cast<const float4*>(yr + c0);
    float4 nv = *reinterpret_cast<const float4*>(ynr + c0);
    unsigned char d0 = code[c0], d1 = code[c0 + 1], d2 = code[c0 + 2], d3 = code[c0 + 3];
    elem(c0,     d0, xv.x, yv.x, nv.x);
    elem(c0 + 1, d1, xv.y, yv.y, nv.y);
    elem(c0 + 2, d2, xv.z, yv.z, nv.z);
    elem(c0 + 3, d3, xv.w, yv.w, nv.w);
  }
  for (int c = t; c < lead; c += 256) elem(c, code[c], xr[c], yr[c], ynr[c]);
  for (int c = lead + (n4 << 2) + t; c < C_; c += 256) elem(c, code[c], xr[c], yr[c], ynr[c]);
  __syncthreads();

  // Tree-reduce the [L][256] per-thread group maxima down to slot[l*256].
  for (int s = 128; s > 0; s >>= 1) {
    if (t < s) {
#pragma unroll
      for (int l = 0; l < L_; ++l) {
        float o = slot[(l << 8) + t + s];
        if (o > slot[(l << 8) + t]) slot[(l << 8) + t] = o;
      }
    }
    __syncthreads();
  }

  // Exact 16th-largest x of the row.
  const int cnt = cand_cnt;
  const bool mainp = (cnt >= TOPK_) && (cnt <= CAP_);
  if (mainp) {
    if (t < 64) {  // wave 0: binary search on ordered keys, candidates in registers
      unsigned int ku[CAP_ / 64];
#pragma unroll
      for (int k = 0; k < CAP_ / 64; ++k) {
        int idx = t + (k << 6);
        ku[k] = (idx < cnt) ? fkey(cand[idx]) : 0u;
      }
      unsigned int lo = 0u, hi = 0xFFFFFFFFu;
      for (int it = 0; it < 32 && lo < hi; ++it) {
        unsigned int mid = lo + ((hi - lo) >> 1) + 1u;
        int c16 = 0;
#pragma unroll
        for (int k = 0; k < CAP_ / 64; ++k) c16 += (ku[k] >= mid) ? 1 : 0;
#pragma unroll
        for (int off = 32; off > 0; off >>= 1) c16 += __shfl_xor(c16, off, 64);
        if (c16 >= TOPK_) lo = mid; else hi = mid - 1u;
      }
      if (t == 0) s_x16 = fkeyinv(lo);
    }
  } else {
    // Fallback (statistically never): exact block-wide counting binary search,
    // re-reading the row from global. Block-uniform control flow -> barriers safe.
    unsigned int lo = 0u, hi = 0xFFFFFFFFu;
    for (int it = 0; it < 32; ++it) {
      if (lo >= hi) break;
      unsigned int mid = lo + ((hi - lo) >> 1) + 1u;
      if (t == 0) s_red = 0;
      __syncthreads();
      int cl = 0;
      for (int c = t; c < C_; c += 256) cl += (fkey(xr[c]) >= mid) ? 1 : 0;
      atomicAdd(&s_red, cl);
      __syncthreads();
      int total = s_red;
      __syncthreads();
      if (total >= TOPK_) lo = mid; else hi = mid - 1u;
    }
    if (t == 0) s_x16 = fkeyinv(lo);
  }
  __syncthreads();

  // Epilogue: 9 sigmoids + 10 rank-loss evaluations per row.
  if (t == 0) {
    float thres = fmaxf(sigm(s_x16), 0.3f);
    unsigned int gtb = gt_bits, gnb = gtn_bits;
    float caseB = 0.0f, unio = -INFINITY, negmax = -INFINITY;
#pragma unroll
    for (int l = 0; l < L_; ++l) {
      float g = sigm(slot[l << 8]);  // sigmoid(max x in group)
      unio = fmaxf(unio, g);         // union_max = max over groups
      caseB += ((gtb >> l) & 1u) ? rank_loss(g, thres) : rank_loss(thres, g);
      if ((gnb >> l) & 1u) negmax = fmaxf(negmax, g);
    }
    float negscore = (gnb != 0u) ? negmax : 0.0f;
    float caseA = 0.5f * rank_loss(thres, unio) + 0.5f * rank_loss(thres, negscore);
    loss[b] = (gtb != 0u) ? caseB : caseA;
  }
}

// Kernel 2: deterministic mean of the 2048 per-row losses.
__global__ void mean_kernel(const float* __restrict__ loss, float* __restrict__ out) {
  const int t = threadIdx.x;
  float s = 0.0f;
  for (int i = t; i < B_; i += 256) s += loss[i];
#pragma unroll
  for (int off = 32; off > 0; off >>= 1) s += __shfl_xor(s, off, 64);
  __shared__ float part[4];
  if ((t & 63) == 0) part[t >> 6] = s;
  __syncthreads();
  if (t == 0) out[0] = (part[0] + part[1] + part[2] + part[3]) * (1.0f / (float)B_);
}

extern "C" void kernel_launch(void* const* d_in, const int* in_sizes, int n_in,
                              void* d_out, int out_size, void* d_ws, size_t ws_size,
                              hipStream_t stream) {
  const float* x = (const float*)d_in[0];
  const float* y = (const float*)d_in[1];
  const float* yn = (const float*)d_in[2];
  const int* mask = (const int*)d_in[3];  // bool promoted to int32 by harness

  float* loss = (float*)d_ws;                                   // 2048 floats
  unsigned char* code = (unsigned char*)d_ws + B_ * sizeof(float);  // 9605 bytes

  hipLaunchKernelGGL(build_code_kernel, dim3((C_ + 255) / 256), dim3(256), 0, stream,
                     mask, code);
  hipLaunchKernelGGL(row_loss_kernel, dim3(B_), dim3(256), 0, stream,
                     x, y, yn, code, loss);
  hipLaunchKernelGGL(mean_kernel, dim3(1), dim3(256), 0, stream,
                     loss, (float*)d_out);
}